// Round 16
// baseline (166.553 us; speedup 1.0000x reference)
//
#include <hip/hip_runtime.h>
#include <math.h>
#include <limits.h>

namespace {
constexpr int kFeat = 112;
constexpr int kBatch = 256;
constexpr int kTotal = 96981;
constexpr int kStride = 116;      // /4 -> float4-aligned columns; cols 113..115 = pad (champion table lives there)
constexpr int kNT = 512;          // 8 waves; 3 blocks/CU (LDS-limited)
constexpr int kRH[13] = {16,12,20,24,20,28,32,24,40,28,40,28,36};
constexpr int kRW[13] = {16,20,12,24,28,20,32,40,24,40,28,36,28};
constexpr int kOff[13] = {0,9409,18802,28195,36116,44021,51926,58487,64984,71481,77686,83891,90436};
// per-ratio quad geometry: nqy = ceil(nc/4), NQ = nr*nqy
constexpr int kNQY[13] = {25,24,26,23,22,24,21,19,23,19,22,20,22};
constexpr int kNQ[13]  = {2425,2424,2418,2047,2046,2040,1701,1691,1679,1615,1606,1700,1694};
// entries: 4 chunks (256 quads) each; NE = ceil(ceil(NQ/64)/4)
constexpr int kNE[13]  = {10,10,10,8,8,8,7,7,7,7,7,7,7};

constexpr int ne_sum(int RB, int RE) {
  int s = 0;
  for (int r = RB; r < RE; ++r) s += kNE[r];
  return s;
}
}

// ---- champion table packed into SAT pad columns (113..115), 12 B/row, 1356 B total ----
// linearized pad byte p -> row p/12, byte p%12 of that row's 12B pad.
// scores: entry e at p = 4e          (e < 64 reserved; 4-byte aligned slots)
// locals: entry e at p = 256 + 2e   (u16; entry spans <= 1023 quads*4+3 < 4096 gi)
__device__ __forceinline__ float* pad_score(float* sat, int e) {
  return sat + (e / 3) * kStride + 113 + (e % 3);
}
__device__ __forceinline__ unsigned short* pad_local16(float* sat, int e) {
  const int p = 256 + 2 * e;
  const int r = p / 12;
  return (unsigned short*)((char*)sat + r * (kStride * 4) + 113 * 4 + (p - r * 12));
}

struct NmsShared {
  float rs[kNT / 64];
  int   ri[kNT / 64];
  float shS; int shI;
  float pX0[3], pY0[3], pX1[3], pY1[3], pA[3];
  unsigned long long dirtyM[kNT / 64];   // per-wave suppressed-champion masks
};

__device__ __forceinline__ void block_argmax(float s, int i, NmsShared* ns) {
  __syncthreads();                       // protect rs/ri reuse across passes
#pragma unroll
  for (int off = 32; off > 0; off >>= 1) {
    const float s2 = __shfl_down(s, off, 64);
    const int   i2 = __shfl_down(i, off, 64);
    if (s2 > s || (s2 == s && i2 < i)) { s = s2; i = i2; }
  }
  const int wave = threadIdx.x >> 6;
  if ((threadIdx.x & 63) == 0) { ns->rs[wave] = s; ns->ri[wave] = i; }
  __syncthreads();
  if (threadIdx.x == 0) {
    float bs = ns->rs[0]; int bi = ns->ri[0];
#pragma unroll
    for (int w = 1; w < kNT / 64; ++w)
      if (ns->rs[w] > bs || (ns->rs[w] == bs && ns->ri[w] < bi)) { bs = ns->rs[w]; bi = ns->ri[w]; }
    ns->shS = bs; ns->shI = bi;
  }
  __syncthreads();
}

// Build 113x113 inclusive SAT (border row/col 0) in LDS, stride 116.
__device__ void build_sat(const float* __restrict__ xb, float* __restrict__ sat) {
  const int tid = threadIdx.x;
  for (int j = tid; j < kStride; j += kNT) sat[j] = 0.f;          // row 0 (+pad)
  for (int r = tid; r < 113; r += kNT) sat[r * kStride] = 0.f;    // col 0
  const float4* x4 = (const float4*)xb;                            // 12544%4==0, base aligned
  for (int i = tid; i < (kFeat * kFeat) / 4; i += kNT) {
    const float4 v = x4[i];
    const int r = i / (kFeat / 4);
    const int c = (i - r * (kFeat / 4)) * 4;
    float* dst = sat + (r + 1) * kStride + c + 1;
    dst[0] = v.x; dst[1] = v.y; dst[2] = v.z; dst[3] = v.w;
  }
  __syncthreads();
  // row inclusive scans: one wave per row, lanes = columns (conflict-free)
  const int wave = tid >> 6, lane = tid & 63;
  for (int r = 1 + wave; r <= kFeat; r += kNT / 64) {
    float* row = sat + r * kStride;
    float v = row[1 + lane];                       // cols 1..64
#pragma unroll
    for (int d = 1; d < 64; d <<= 1) { const float u = __shfl_up(v, d, 64); if (lane >= d) v += u; }
    row[1 + lane] = v;
    const float tot = __shfl(v, 63, 64);
    const int c = 65 + lane;                       // cols 65..112
    float w = (c <= kFeat) ? row[c] : 0.f;
#pragma unroll
    for (int d = 1; d < 64; d <<= 1) { const float u = __shfl_up(w, d, 64); if (lane >= d) w += u; }
    if (c <= kFeat) row[c] = w + tot;
  }
  __syncthreads();
  // column scans, 4 segments of 28 rows: serial chain cut 112 -> 28
  const int seg = tid / kFeat;            // 0..3 for tid < 448
  const int col = tid - seg * kFeat + 1;  // 1..112
  if (tid < 4 * kFeat) {
    const int r0 = seg * 28 + 1;
    float s = 0.f;
    for (int r = r0; r < r0 + 28; ++r) { s += sat[r * kStride + col]; sat[r * kStride + col] = s; }
  }
  __syncthreads();
  float off = 0.f;
  if (tid < 4 * kFeat && seg > 0) {
#pragma unroll
    for (int s2 = 1; s2 <= 3; ++s2)
      if (s2 <= seg) off += sat[(28 * s2) * kStride + col];
  }
  __syncthreads();
  if (tid < 4 * kFeat && seg > 0) {
    const int r0 = seg * 28 + 1;
    for (int r = r0; r < r0 + 28; ++r) sat[r * kStride + col] += off;
  }
  __syncthreads();
}

// idx -> window geometry (same arithmetic as reference coords).
template<int RB, int RE>
__device__ __forceinline__ void decode_geom(int pi, float& x0, float& y0,
                                            float& x1, float& y1, float& a) {
  x0 = 0.f; y0 = 0.f; x1 = 0.f; y1 = 0.f; a = 0.f;
#pragma unroll
  for (int rr = RB; rr < RE; ++rr) {
    const int nr = kFeat - kRH[rr] + 1, nc = kFeat - kRW[rr] + 1;
    if (pi >= kOff[rr] && pi < kOff[rr] + nr * nc) {
      const int l = pi - kOff[rr];
      const int xi = l / nc, yi = l - xi * nc;
      const float x0u = xi * 4.0f - 1.0f, y0u = yi * 4.0f - 1.0f;
      x1 = x0u + kRH[rr] * 4.0f; y1 = y0u + kRW[rr] * 4.0f;
      x0 = fmaxf(x0u, 0.0f); y0 = fmaxf(y0u, 0.0f);
      a = (x1 - x0 + 1.0f) * (y1 - y0 + 1.0f);
    }
  }
}

// entry e -> its champion's gi (compile-time nqy/nc per unrolled ratio branch).
template<int RB, int RE>
__device__ __forceinline__ int entry_gi(float* sat, int e) {
  const int local = (int)*pad_local16(sat, e);
  int gi = 0, eb = 0;
#pragma unroll
  for (int rr = RB; rr < RE; ++rr) {
    if (e >= eb && e < eb + kNE[rr]) {
      const int nqy = kNQY[rr], nc = kFeat - kRW[rr] + 1;
      const int qb0 = (e - eb) << 8;               // entry base quad (4 chunks)
      const int bxi = qb0 / nqy;
      gi = kOff[rr] + bxi * nc + ((qb0 - bxi * nqy) << 2) + local;
    }
    eb += kNE[rr];
  }
  return gi;
}

// After block_argmax over (score, entry): thread 0 resolves entry -> gi,
// stores pick geometry + outputs. Entry order == gi order, so lowest-entry
// ties == lowest-gi ties (reference jnp.argmax semantics).
template<int RB, int RE>
__device__ __forceinline__ void pick_store(float* sat, NmsShared* ns, int k, int slot,
                                           float* __restrict__ out_idx,
                                           float* __restrict__ out_sc, int b) {
  if (threadIdx.x == 0) {
    const int gi = entry_gi<RB, RE>(sat, ns->shI);
    float x0, y0, x1, y1, a;
    decode_geom<RB, RE>(gi, x0, y0, x1, y1, a);
    ns->pX0[k] = x0; ns->pY0[k] = y0; ns->pX1[k] = x1; ns->pY1[k] = y1; ns->pA[k] = a;
    out_idx[b * 7 + slot + k] = (float)gi;
    out_sc [b * 7 + slot + k] = ns->shS;
  }
  __syncthreads();
}

// Wave-cooperative rescan of dirty entry e (4 chunks) vs picks 0..k-1; refills entry.
template<int RB, int RE, int NP>
__device__ __forceinline__ void rescan_entry(float* sat, NmsShared* ns, int e, int k,
                                             int lane) {
  int ebase = 0;
#pragma unroll
  for (int rr = RB; rr < RE; ++rr) {
    if (e >= ebase && e < ebase + kNE[rr]) {
      const int rh = kRH[rr], rw = kRW[rr];
      const int nc = kFeat - rw + 1;
      const int nqy = kNQY[rr];
      const int NQ = kNQ[rr];
      const float inv = 1.0f / (float)(rh * rw);
      const int eL = e - ebase;
      float bs = -INFINITY; int bgi = INT_MAX;
#pragma unroll
      for (int c = 0; c < 4; ++c) {
        const int qb = ((eL << 2) + c) << 6;
        if (qb >= NQ) break;                       // wave-uniform
        const int q = qb + lane;
        const bool act = q < NQ;
        const int qc = act ? q : NQ - 1;
        const int xi = qc / nqy, qy = qc - xi * nqy;
        const int yi0 = qy << 2;
        const float* u = sat + xi * kStride;
        const float* d = u + rh * kStride;
        const float4 U0 = *(const float4*)(u + yi0);
        const float4 U1 = *(const float4*)(u + yi0 + rw);
        const float4 D0 = *(const float4*)(d + yi0);
        const float4 D1 = *(const float4*)(d + yi0 + rw);
        float s4[4];
        s4[0] = (D1.x - U1.x - D0.x + U0.x) * inv;
        s4[1] = (D1.y - U1.y - D0.y + U0.y) * inv;
        s4[2] = (D1.z - U1.z - D0.z + U0.z) * inv;
        s4[3] = (D1.w - U1.w - D0.w + U0.w) * inv;
        const float X0u = xi * 4.0f - 1.0f;
        const float X1 = X0u + rh * 4.0f;
        const float X0 = fmaxf(X0u, 0.0f);
        const float Ax = X1 - X0 + 1.0f;
        float wxp[NP > 1 ? NP - 1 : 1];
#pragma unroll
        for (int p = 0; p < NP - 1; ++p)
          if (p < k) wxp[p] = fminf(X1, ns->pX1[p]) - fmaxf(X0, ns->pX0[p]) + 1.0f;
        const int gi0 = kOff[rr] + xi * nc + yi0;
        const int rem = nc - yi0;
        if (act) {
#pragma unroll
          for (int j = 0; j < 4; ++j) {
            if (j >= rem) break;
            const float Y0u = (yi0 + j) * 4.0f - 1.0f;
            const float Y1 = Y0u + rw * 4.0f;
            const float Y0 = fmaxf(Y0u, 0.0f);
            const float A = Ax * (Y1 - Y0 + 1.0f);
            bool alive = true;
#pragma unroll
            for (int p = 0; p < NP - 1; ++p) {
              if (p >= k) break;
              const float hyp = fminf(Y1, ns->pY1[p]) - fmaxf(Y0, ns->pY0[p]) + 1.0f;
              alive &= !((wxp[p] >= 0.0f) & (hyp >= 0.0f) &
                         (5.0f * wxp[p] * hyp > A + ns->pA[p]));
            }
            if (alive && s4[j] > bs) { bs = s4[j]; bgi = gi0 + j; }  // per-lane gi monotone
          }
        }
      }
      // (s, gi) reduce: lowest gi on ties
#pragma unroll
      for (int off = 32; off > 0; off >>= 1) {
        const float s2 = __shfl_down(bs, off, 64);
        const int   i2 = __shfl_down(bgi, off, 64);
        if (s2 > bs || (s2 == bs && i2 < bgi)) { bs = s2; bgi = i2; }
      }
      if (lane == 0) {
        const int qb0 = eL << 8;
        const int bxi = qb0 / nqy;
        const int giBase = kOff[rr] + bxi * nc + ((qb0 - bxi * nqy) << 2);
        *pad_score(sat, e) = bs;
        *pad_local16(sat, e) =
            (unsigned short)((bgi == INT_MAX) ? 0 : (bgi - giBase));
      }
    }
    ebase += kNE[rr];
  }
}

// Score this group's ratios once (write wb), building a per-256-quad-entry
// champion table in the SAT's pad columns (zero extra LDS). One wave-reduce
// per entry (4 chunks amortized). NMS re-passes: lane-parallel champion test
// (entry e <-> thread e), ballot-collected dirty set, dirty entries rescanned
// by waves in round-robin (exact: a surviving champion remains its entry's
// alive-max since the alive set only shrinks). Lowest-index ties preserved.
template<int RB, int RE, int NP, int SLOT>
__device__ void run_group(float* sat, NmsShared* ns,
                          float* __restrict__ wb,
                          float* __restrict__ out_idx, float* __restrict__ out_sc, int b) {
  constexpr int NEtot = ne_sum(RB, RE);
  const int tid = threadIdx.x;
  const int lane = tid & 63;
  const int wave = tid >> 6;

  // ---- pass 0: quad-vectorized scoring; per-lane running max over the
  //      entry's 4 chunks, ONE (s,gi) wave-reduce per entry ----
  int eb = 0;
#pragma unroll
  for (int rr = RB; rr < RE; ++rr) {
    const int rh = kRH[rr], rw = kRW[rr];
    const int nc = kFeat - rw + 1;
    const int nqy = kNQY[rr];
    const int NQ = kNQ[rr];
    const int NE = kNE[rr];
    const float inv = 1.0f / (float)(rh * rw);
    for (int e = wave; e < NE; e += kNT / 64) {        // wave-uniform entry
      float bs = -INFINITY; int bgi = INT_MAX;
#pragma unroll
      for (int c = 0; c < 4; ++c) {
        const int qb = ((e << 2) + c) << 6;
        if (qb >= NQ) break;                           // wave-uniform
        const int q = qb + lane;
        const bool act = q < NQ;
        const int qc = act ? q : NQ - 1;               // clamp for safe addressing
        const int xi = qc / nqy, qy = qc - xi * nqy;   // compile-time nqy -> magic mul
        const int yi0 = qy << 2;
        const float* u = sat + xi * kStride;
        const float* d = u + rh * kStride;
        const float4 U0 = *(const float4*)(u + yi0);
        const float4 U1 = *(const float4*)(u + yi0 + rw);
        const float4 D0 = *(const float4*)(d + yi0);
        const float4 D1 = *(const float4*)(d + yi0 + rw);
        const float s0 = (D1.x - U1.x - D0.x + U0.x) * inv;
        const float s1 = (D1.y - U1.y - D0.y + U0.y) * inv;
        const float s2 = (D1.z - U1.z - D0.z + U0.z) * inv;
        const float s3 = (D1.w - U1.w - D0.w + U0.w) * inv;
        const int gi0 = kOff[rr] + xi * nc + yi0;
        const int rem = nc - yi0;                      // >= 1 for active quads
        if (act) {
          float* w = wb + gi0;
          // per-lane gi strictly increases across j and chunks -> keep-first
          w[0] = s0; if (s0 > bs) { bs = s0; bgi = gi0; }
          if (rem > 1) { w[1] = s1; if (s1 > bs) { bs = s1; bgi = gi0 + 1; } }
          if (rem > 2) { w[2] = s2; if (s2 > bs) { bs = s2; bgi = gi0 + 2; } }
          if (rem > 3) { w[3] = s3; if (s3 > bs) { bs = s3; bgi = gi0 + 3; } }
        }
      }
      // (s, gi) reduce: lowest gi on ties (= reference argmax order)
#pragma unroll
      for (int off = 32; off > 0; off >>= 1) {
        const float s2 = __shfl_down(bs, off, 64);
        const int   i2 = __shfl_down(bgi, off, 64);
        if (s2 > bs || (s2 == bs && i2 < bgi)) { bs = s2; bgi = i2; }
      }
      if (lane == 0) {
        const int qb0 = e << 8;
        const int bxi = qb0 / nqy;
        const int giBase = kOff[rr] + bxi * nc + ((qb0 - bxi * nqy) << 2);
        *pad_score(sat, eb + e) = bs;
        *pad_local16(sat, eb + e) = (unsigned short)(bgi - giBase);
      }
    }
    eb += kNE[rr];
  }
  __syncthreads();   // table complete

  // ---- pick 0: block argmax over champion table ----
  {
    const float s = (tid < NEtot) ? *pad_score(sat, tid) : -INFINITY;
    const int   i = (tid < NEtot) ? tid : INT_MAX;
    block_argmax(s, i, ns);
  }
  pick_store<RB, RE>(sat, ns, 0, SLOT, out_idx, out_sc, b);

  // ---- picks 1..NP-1 ----
  // iou > 0.25  <=>  5*inter > A + pa  (integer-valued floats -> exact).
  // Self-window: inter == A == pa -> suppressed (handles idx removal).
  for (int k = 1; k < NP; ++k) {
    const float nx0 = ns->pX0[k-1], ny0 = ns->pY0[k-1];
    const float nx1 = ns->pX1[k-1], ny1 = ns->pY1[k-1], na = ns->pA[k-1];

    // (1) lane-parallel champion test vs the NEWEST pick only (older picks
    //     already filtered the table on previous iterations)
    bool sup = false;
    if (tid < NEtot) {
      const float es = *pad_score(sat, tid);
      if (es != -INFINITY) {
        const int gi = entry_gi<RB, RE>(sat, tid);
        float x0, y0, x1, y1, a;
        decode_geom<RB, RE>(gi, x0, y0, x1, y1, a);
        const float twx = fminf(x1, nx1) - fmaxf(x0, nx0) + 1.0f;
        const float thy = fminf(y1, ny1) - fmaxf(y0, ny0) + 1.0f;
        sup = (twx >= 0.0f) & (thy >= 0.0f) & (5.0f * twx * thy > a + na);
      }
    }
    const unsigned long long m0 = __ballot(sup);
    if (lane == 0) ns->dirtyM[wave] = m0;
    __syncthreads();

    // (2) dirty entries: round-robin across waves (load-balanced)
    int cnt = 0;
#pragma unroll
    for (int wm = 0; wm < kNT / 64; ++wm) {
      unsigned long long m = ns->dirtyM[wm];
      while (m) {
        const int bit = __ffsll(m) - 1;
        m &= m - 1;
        if ((cnt & 7) == wave) {
          rescan_entry<RB, RE, NP>(sat, ns, (wm << 6) + bit, k, lane);
        }
        ++cnt;
      }
    }
    __syncthreads();   // table updates visible

    // (3) argmax + store
    {
      const float s = (tid < NEtot) ? *pad_score(sat, tid) : -INFINITY;
      const int   i = (tid < NEtot) ? tid : INT_MAX;
      block_argmax(s, i, ns);
    }
    pick_store<RB, RE>(sat, ns, k, SLOT, out_idx, out_sc, b);
  }
}

__global__ __launch_bounds__(kNT, 6) void appm_fused(const float* __restrict__ x,
                                                     float* __restrict__ win,
                                                     float* __restrict__ out_idx,
                                                     float* __restrict__ out_sc) {
  __shared__ __align__(16) float sat[113 * kStride];   // 52,432 B (pad cols host the table)
  __shared__ NmsShared ns;
  const int b = blockIdx.x / 3;
  const int t = blockIdx.x % 3;      // group id: each block handles one NMS group

  build_sat(x + (size_t)b * kFeat * kFeat, sat);

  float* wb = win + (size_t)b * kTotal;
  if (t == 0)       run_group<0, 3, 2, 0>(sat, &ns, wb, out_idx, out_sc, b);
  else if (t == 1)  run_group<3, 6, 3, 2>(sat, &ns, wb, out_idx, out_sc, b);
  else              run_group<6, 13, 2, 5>(sat, &ns, wb, out_idx, out_sc, b);
}

extern "C" void kernel_launch(void* const* d_in, const int* in_sizes, int n_in,
                              void* d_out, int out_size, void* d_ws, size_t ws_size,
                              hipStream_t stream) {
  const float* x = (const float*)d_in[0];
  float* out     = (float*)d_out;
  float* out_idx = out;                      // (256,7) indices as float values
  float* out_sc  = out + kBatch * 7;         // (256,7) picked scores
  float* win     = out + 2 * kBatch * 7;     // (256,96981) window scores

  appm_fused<<<kBatch * 3, kNT, 0, stream>>>(x, win, out_idx, out_sc);
}

// Round 17
// 157.160 us; speedup vs baseline: 1.0598x; 1.0598x over previous
//
#include <hip/hip_runtime.h>
#include <math.h>
#include <limits.h>
#include <string.h>

namespace {
constexpr int kFeat = 112;
constexpr int kBatch = 256;
constexpr int kTotal = 96981;
constexpr int kStride = 116;      // /4 -> float4-aligned columns; cols 113..115 = pad (champion table lives there)
constexpr int kNT = 512;          // 8 waves; 3 blocks/CU (LDS-limited)
constexpr int kRH[13] = {16,12,20,24,20,28,32,24,40,28,40,28,36};
constexpr int kRW[13] = {16,20,12,24,28,20,32,40,24,40,28,36,28};
constexpr int kOff[13] = {0,9409,18802,28195,36116,44021,51926,58487,64984,71481,77686,83891,90436};
// per-ratio quad geometry: nqy = ceil(nc/4), NQ = nr*nqy
constexpr int kNQY[13] = {25,24,26,23,22,24,21,19,23,19,22,20,22};
constexpr int kNQ[13]  = {2425,2424,2418,2047,2046,2040,1701,1691,1679,1615,1606,1700,1694};
// entries: 4 chunks (256 quads) each; NE = ceil(ceil(NQ/64)/4)
constexpr int kNE[13]  = {10,10,10,8,8,8,7,7,7,7,7,7,7};

constexpr int ne_sum(int RB, int RE) {
  int s = 0;
  for (int r = RB; r < RE; ++r) s += kNE[r];
  return s;
}
}

// ---- champion table packed into SAT pad columns (113..115), 12 B/row, 1356 B total ----
// linearized pad byte p -> row p/12, byte p%12 of that row's 12B pad.
// scores: entry e at p = 4e          (e < 64 reserved; 4-byte aligned slots)
// locals: entry e at p = 256 + 2e   (u16; entry spans <= 1023 quads*4+3 < 4096 gi)
__device__ __forceinline__ float* pad_score(float* sat, int e) {
  return sat + (e / 3) * kStride + 113 + (e % 3);
}
__device__ __forceinline__ unsigned short* pad_local16(float* sat, int e) {
  const int p = 256 + 2 * e;
  const int r = p / 12;
  return (unsigned short*)((char*)sat + r * (kStride * 4) + 113 * 4 + (p - r * 12));
}

struct NmsShared {
  float rs[kNT / 64];
  int   ri[kNT / 64];
  float shS; int shI;
  float pX0[3], pY0[3], pX1[3], pY1[3], pA[3];
  unsigned long long dirtyM[kNT / 64];   // per-wave suppressed-champion masks
};

__device__ __forceinline__ void block_argmax(float s, int i, NmsShared* ns) {
  __syncthreads();                       // protect rs/ri reuse across passes
#pragma unroll
  for (int off = 32; off > 0; off >>= 1) {
    const float s2 = __shfl_down(s, off, 64);
    const int   i2 = __shfl_down(i, off, 64);
    if (s2 > s || (s2 == s && i2 < i)) { s = s2; i = i2; }
  }
  const int wave = threadIdx.x >> 6;
  if ((threadIdx.x & 63) == 0) { ns->rs[wave] = s; ns->ri[wave] = i; }
  __syncthreads();
  if (threadIdx.x == 0) {
    float bs = ns->rs[0]; int bi = ns->ri[0];
#pragma unroll
    for (int w = 1; w < kNT / 64; ++w)
      if (ns->rs[w] > bs || (ns->rs[w] == bs && ns->ri[w] < bi)) { bs = ns->rs[w]; bi = ns->ri[w]; }
    ns->shS = bs; ns->shI = bi;
  }
  __syncthreads();
}

// Build 113x113 inclusive SAT (border row/col 0) in LDS, stride 116.
__device__ void build_sat(const float* __restrict__ xb, float* __restrict__ sat) {
  const int tid = threadIdx.x;
  for (int j = tid; j < kStride; j += kNT) sat[j] = 0.f;          // row 0 (+pad)
  for (int r = tid; r < 113; r += kNT) sat[r * kStride] = 0.f;    // col 0
  const float4* x4 = (const float4*)xb;                            // 12544%4==0, base aligned
  for (int i = tid; i < (kFeat * kFeat) / 4; i += kNT) {
    const float4 v = x4[i];
    const int r = i / (kFeat / 4);
    const int c = (i - r * (kFeat / 4)) * 4;
    float* dst = sat + (r + 1) * kStride + c + 1;
    dst[0] = v.x; dst[1] = v.y; dst[2] = v.z; dst[3] = v.w;
  }
  __syncthreads();
  // row inclusive scans: one wave per row, lanes = columns (conflict-free)
  const int wave = tid >> 6, lane = tid & 63;
  for (int r = 1 + wave; r <= kFeat; r += kNT / 64) {
    float* row = sat + r * kStride;
    float v = row[1 + lane];                       // cols 1..64
#pragma unroll
    for (int d = 1; d < 64; d <<= 1) { const float u = __shfl_up(v, d, 64); if (lane >= d) v += u; }
    row[1 + lane] = v;
    const float tot = __shfl(v, 63, 64);
    const int c = 65 + lane;                       // cols 65..112
    float w = (c <= kFeat) ? row[c] : 0.f;
#pragma unroll
    for (int d = 1; d < 64; d <<= 1) { const float u = __shfl_up(w, d, 64); if (lane >= d) w += u; }
    if (c <= kFeat) row[c] = w + tot;
  }
  __syncthreads();
  // column scans, 4 segments of 28 rows: serial chain cut 112 -> 28
  const int seg = tid / kFeat;            // 0..3 for tid < 448
  const int col = tid - seg * kFeat + 1;  // 1..112
  if (tid < 4 * kFeat) {
    const int r0 = seg * 28 + 1;
    float s = 0.f;
    for (int r = r0; r < r0 + 28; ++r) { s += sat[r * kStride + col]; sat[r * kStride + col] = s; }
  }
  __syncthreads();
  float off = 0.f;
  if (tid < 4 * kFeat && seg > 0) {
#pragma unroll
    for (int s2 = 1; s2 <= 3; ++s2)
      if (s2 <= seg) off += sat[(28 * s2) * kStride + col];
  }
  __syncthreads();
  if (tid < 4 * kFeat && seg > 0) {
    const int r0 = seg * 28 + 1;
    for (int r = r0; r < r0 + 28; ++r) sat[r * kStride + col] += off;
  }
  __syncthreads();
}

// idx -> window geometry (same arithmetic as reference coords).
template<int RB, int RE>
__device__ __forceinline__ void decode_geom(int pi, float& x0, float& y0,
                                            float& x1, float& y1, float& a) {
  x0 = 0.f; y0 = 0.f; x1 = 0.f; y1 = 0.f; a = 0.f;
#pragma unroll
  for (int rr = RB; rr < RE; ++rr) {
    const int nr = kFeat - kRH[rr] + 1, nc = kFeat - kRW[rr] + 1;
    if (pi >= kOff[rr] && pi < kOff[rr] + nr * nc) {
      const int l = pi - kOff[rr];
      const int xi = l / nc, yi = l - xi * nc;
      const float x0u = xi * 4.0f - 1.0f, y0u = yi * 4.0f - 1.0f;
      x1 = x0u + kRH[rr] * 4.0f; y1 = y0u + kRW[rr] * 4.0f;
      x0 = fmaxf(x0u, 0.0f); y0 = fmaxf(y0u, 0.0f);
      a = (x1 - x0 + 1.0f) * (y1 - y0 + 1.0f);
    }
  }
}

// entry e -> its champion's gi (compile-time nqy/nc per unrolled ratio branch).
template<int RB, int RE>
__device__ __forceinline__ int entry_gi(float* sat, int e) {
  const int local = (int)*pad_local16(sat, e);
  int gi = 0, eb = 0;
#pragma unroll
  for (int rr = RB; rr < RE; ++rr) {
    if (e >= eb && e < eb + kNE[rr]) {
      const int nqy = kNQY[rr], nc = kFeat - kRW[rr] + 1;
      const int qb0 = (e - eb) << 8;               // entry base quad (4 chunks)
      const int bxi = qb0 / nqy;
      gi = kOff[rr] + bxi * nc + ((qb0 - bxi * nqy) << 2) + local;
    }
    eb += kNE[rr];
  }
  return gi;
}

// After block_argmax over (score, entry): thread 0 resolves entry -> gi,
// stores pick geometry + outputs. Entry order == gi order, so lowest-entry
// ties == lowest-gi ties (reference jnp.argmax semantics).
template<int RB, int RE>
__device__ __forceinline__ void pick_store(float* sat, NmsShared* ns, int k, int slot,
                                           float* __restrict__ out_idx,
                                           float* __restrict__ out_sc, int b) {
  if (threadIdx.x == 0) {
    const int gi = entry_gi<RB, RE>(sat, ns->shI);
    float x0, y0, x1, y1, a;
    decode_geom<RB, RE>(gi, x0, y0, x1, y1, a);
    ns->pX0[k] = x0; ns->pY0[k] = y0; ns->pX1[k] = x1; ns->pY1[k] = y1; ns->pA[k] = a;
    out_idx[b * 7 + slot + k] = (float)gi;
    out_sc [b * 7 + slot + k] = ns->shS;
  }
  __syncthreads();
}

// Wave-cooperative rescan of dirty entry e (4 chunks) vs picks 0..k-1; refills entry.
template<int RB, int RE, int NP>
__device__ __forceinline__ void rescan_entry(float* sat, NmsShared* ns, int e, int k,
                                             int lane) {
  int ebase = 0;
#pragma unroll
  for (int rr = RB; rr < RE; ++rr) {
    if (e >= ebase && e < ebase + kNE[rr]) {
      const int rh = kRH[rr], rw = kRW[rr];
      const int nc = kFeat - rw + 1;
      const int nqy = kNQY[rr];
      const int NQ = kNQ[rr];
      const float inv = 1.0f / (float)(rh * rw);
      const int eL = e - ebase;
      float bs = -INFINITY; int bgi = INT_MAX;
#pragma unroll
      for (int c = 0; c < 4; ++c) {
        const int qb = ((eL << 2) + c) << 6;
        if (qb >= NQ) break;                       // wave-uniform
        const int q = qb + lane;
        const bool act = q < NQ;
        const int qc = act ? q : NQ - 1;
        const int xi = qc / nqy, qy = qc - xi * nqy;
        const int yi0 = qy << 2;
        const float* u = sat + xi * kStride;
        const float* d = u + rh * kStride;
        const float4 U0 = *(const float4*)(u + yi0);
        const float4 U1 = *(const float4*)(u + yi0 + rw);
        const float4 D0 = *(const float4*)(d + yi0);
        const float4 D1 = *(const float4*)(d + yi0 + rw);
        float s4[4];
        s4[0] = (D1.x - U1.x - D0.x + U0.x) * inv;
        s4[1] = (D1.y - U1.y - D0.y + U0.y) * inv;
        s4[2] = (D1.z - U1.z - D0.z + U0.z) * inv;
        s4[3] = (D1.w - U1.w - D0.w + U0.w) * inv;
        const float X0u = xi * 4.0f - 1.0f;
        const float X1 = X0u + rh * 4.0f;
        const float X0 = fmaxf(X0u, 0.0f);
        const float Ax = X1 - X0 + 1.0f;
        float wxp[NP > 1 ? NP - 1 : 1];
#pragma unroll
        for (int p = 0; p < NP - 1; ++p)
          if (p < k) wxp[p] = fminf(X1, ns->pX1[p]) - fmaxf(X0, ns->pX0[p]) + 1.0f;
        const int gi0 = kOff[rr] + xi * nc + yi0;
        const int rem = nc - yi0;
        if (act) {
#pragma unroll
          for (int j = 0; j < 4; ++j) {
            if (j >= rem) break;
            const float Y0u = (yi0 + j) * 4.0f - 1.0f;
            const float Y1 = Y0u + rw * 4.0f;
            const float Y0 = fmaxf(Y0u, 0.0f);
            const float A = Ax * (Y1 - Y0 + 1.0f);
            bool alive = true;
#pragma unroll
            for (int p = 0; p < NP - 1; ++p) {
              if (p >= k) break;
              const float hyp = fminf(Y1, ns->pY1[p]) - fmaxf(Y0, ns->pY0[p]) + 1.0f;
              alive &= !((wxp[p] >= 0.0f) & (hyp >= 0.0f) &
                         (5.0f * wxp[p] * hyp > A + ns->pA[p]));
            }
            if (alive && s4[j] > bs) { bs = s4[j]; bgi = gi0 + j; }  // per-lane gi monotone
          }
        }
      }
      // (s, gi) reduce: lowest gi on ties
#pragma unroll
      for (int off = 32; off > 0; off >>= 1) {
        const float s2 = __shfl_down(bs, off, 64);
        const int   i2 = __shfl_down(bgi, off, 64);
        if (s2 > bs || (s2 == bs && i2 < bgi)) { bs = s2; bgi = i2; }
      }
      if (lane == 0) {
        const int qb0 = eL << 8;
        const int bxi = qb0 / nqy;
        const int giBase = kOff[rr] + bxi * nc + ((qb0 - bxi * nqy) << 2);
        *pad_score(sat, e) = bs;
        *pad_local16(sat, e) =
            (unsigned short)((bgi == INT_MAX) ? 0 : (bgi - giBase));
      }
    }
    ebase += kNE[rr];
  }
}

// Score this group's ratios once (write wb via coalesced 16B stores), building
// a per-256-quad-entry champion table in the SAT's pad columns. One wave-reduce
// per entry. NMS re-passes: lane-parallel champion test, ballot dirty set,
// round-robin dirty rescans. Lowest-index ties preserved at every level.
template<int RB, int RE, int NP, int SLOT>
__device__ void run_group(float* sat, NmsShared* ns,
                          float* __restrict__ wb,
                          float* __restrict__ out_idx, float* __restrict__ out_sc, int b) {
  constexpr int NEtot = ne_sum(RB, RE);
  const int tid = threadIdx.x;
  const int lane = tid & 63;
  const int wave = tid >> 6;

  // ---- pass 0: quad-vectorized scoring; per-lane running max over the
  //      entry's 4 chunks, ONE (s,gi) wave-reduce per entry ----
  int eb = 0;
#pragma unroll
  for (int rr = RB; rr < RE; ++rr) {
    const int rh = kRH[rr], rw = kRW[rr];
    const int nc = kFeat - rw + 1;
    const int nqy = kNQY[rr];
    const int NQ = kNQ[rr];
    const int NE = kNE[rr];
    const float inv = 1.0f / (float)(rh * rw);
    for (int e = wave; e < NE; e += kNT / 64) {        // wave-uniform entry
      float bs = -INFINITY; int bgi = INT_MAX;
#pragma unroll
      for (int c = 0; c < 4; ++c) {
        const int qb = ((e << 2) + c) << 6;
        if (qb >= NQ) break;                           // wave-uniform
        const int q = qb + lane;
        const bool act = q < NQ;
        const int qc = act ? q : NQ - 1;               // clamp for safe addressing
        const int xi = qc / nqy, qy = qc - xi * nqy;   // compile-time nqy -> magic mul
        const int yi0 = qy << 2;
        const float* u = sat + xi * kStride;
        const float* d = u + rh * kStride;
        const float4 U0 = *(const float4*)(u + yi0);
        const float4 U1 = *(const float4*)(u + yi0 + rw);
        const float4 D0 = *(const float4*)(d + yi0);
        const float4 D1 = *(const float4*)(d + yi0 + rw);
        const float s0 = (D1.x - U1.x - D0.x + U0.x) * inv;
        const float s1 = (D1.y - U1.y - D0.y + U0.y) * inv;
        const float s2 = (D1.z - U1.z - D0.z + U0.z) * inv;
        const float s3 = (D1.w - U1.w - D0.w + U0.w) * inv;
        const int gi0 = kOff[rr] + xi * nc + yi0;
        const int rem = nc - yi0;                      // >= 1 for active quads
        if (act) {
          float* w = wb + gi0;
          // per-lane gi strictly increases across j and chunks -> keep-first
          if (rem > 3) {
            // one 16B store per quad (4B-aligned: row base not 16B-aligned).
            // gfx950 supports 4B-aligned multi-dword stores; memcpy carries
            // the true alignment so codegen can emit global_store_dwordx4.
            float4 v; v.x = s0; v.y = s1; v.z = s2; v.w = s3;
            __builtin_memcpy(w, &v, sizeof(float4));
            if (s0 > bs) { bs = s0; bgi = gi0; }
            if (s1 > bs) { bs = s1; bgi = gi0 + 1; }
            if (s2 > bs) { bs = s2; bgi = gi0 + 2; }
            if (s3 > bs) { bs = s3; bgi = gi0 + 3; }
          } else {
            w[0] = s0; if (s0 > bs) { bs = s0; bgi = gi0; }
            if (rem > 1) { w[1] = s1; if (s1 > bs) { bs = s1; bgi = gi0 + 1; } }
            if (rem > 2) { w[2] = s2; if (s2 > bs) { bs = s2; bgi = gi0 + 2; } }
          }
        }
      }
      // (s, gi) reduce: lowest gi on ties (= reference argmax order)
#pragma unroll
      for (int off = 32; off > 0; off >>= 1) {
        const float s2 = __shfl_down(bs, off, 64);
        const int   i2 = __shfl_down(bgi, off, 64);
        if (s2 > bs || (s2 == bs && i2 < bgi)) { bs = s2; bgi = i2; }
      }
      if (lane == 0) {
        const int qb0 = e << 8;
        const int bxi = qb0 / nqy;
        const int giBase = kOff[rr] + bxi * nc + ((qb0 - bxi * nqy) << 2);
        *pad_score(sat, eb + e) = bs;
        *pad_local16(sat, eb + e) = (unsigned short)(bgi - giBase);
      }
    }
    eb += kNE[rr];
  }
  __syncthreads();   // table complete

  // ---- pick 0: block argmax over champion table ----
  {
    const float s = (tid < NEtot) ? *pad_score(sat, tid) : -INFINITY;
    const int   i = (tid < NEtot) ? tid : INT_MAX;
    block_argmax(s, i, ns);
  }
  pick_store<RB, RE>(sat, ns, 0, SLOT, out_idx, out_sc, b);

  // ---- picks 1..NP-1 ----
  // iou > 0.25  <=>  5*inter > A + pa  (integer-valued floats -> exact).
  // Self-window: inter == A == pa -> suppressed (handles idx removal).
  for (int k = 1; k < NP; ++k) {
    const float nx0 = ns->pX0[k-1], ny0 = ns->pY0[k-1];
    const float nx1 = ns->pX1[k-1], ny1 = ns->pY1[k-1], na = ns->pA[k-1];

    // (1) lane-parallel champion test vs the NEWEST pick only (older picks
    //     already filtered the table on previous iterations)
    bool sup = false;
    if (tid < NEtot) {
      const float es = *pad_score(sat, tid);
      if (es != -INFINITY) {
        const int gi = entry_gi<RB, RE>(sat, tid);
        float x0, y0, x1, y1, a;
        decode_geom<RB, RE>(gi, x0, y0, x1, y1, a);
        const float twx = fminf(x1, nx1) - fmaxf(x0, nx0) + 1.0f;
        const float thy = fminf(y1, ny1) - fmaxf(y0, ny0) + 1.0f;
        sup = (twx >= 0.0f) & (thy >= 0.0f) & (5.0f * twx * thy > a + na);
      }
    }
    const unsigned long long m0 = __ballot(sup);
    if (lane == 0) ns->dirtyM[wave] = m0;
    __syncthreads();

    // (2) dirty entries: round-robin across waves (load-balanced)
    int cnt = 0;
#pragma unroll
    for (int wm = 0; wm < kNT / 64; ++wm) {
      unsigned long long m = ns->dirtyM[wm];
      while (m) {
        const int bit = __ffsll(m) - 1;
        m &= m - 1;
        if ((cnt & 7) == wave) {
          rescan_entry<RB, RE, NP>(sat, ns, (wm << 6) + bit, k, lane);
        }
        ++cnt;
      }
    }
    __syncthreads();   // table updates visible

    // (3) argmax + store
    {
      const float s = (tid < NEtot) ? *pad_score(sat, tid) : -INFINITY;
      const int   i = (tid < NEtot) ? tid : INT_MAX;
      block_argmax(s, i, ns);
    }
    pick_store<RB, RE>(sat, ns, k, SLOT, out_idx, out_sc, b);
  }
}

__global__ __launch_bounds__(kNT, 6) void appm_fused(const float* __restrict__ x,
                                                     float* __restrict__ win,
                                                     float* __restrict__ out_idx,
                                                     float* __restrict__ out_sc) {
  __shared__ __align__(16) float sat[113 * kStride];   // 52,432 B (pad cols host the table)
  __shared__ NmsShared ns;
  const int b = blockIdx.x / 3;
  const int t = blockIdx.x % 3;      // group id: each block handles one NMS group

  build_sat(x + (size_t)b * kFeat * kFeat, sat);

  float* wb = win + (size_t)b * kTotal;
  if (t == 0)       run_group<0, 3, 2, 0>(sat, &ns, wb, out_idx, out_sc, b);
  else if (t == 1)  run_group<3, 6, 3, 2>(sat, &ns, wb, out_idx, out_sc, b);
  else              run_group<6, 13, 2, 5>(sat, &ns, wb, out_idx, out_sc, b);
}

extern "C" void kernel_launch(void* const* d_in, const int* in_sizes, int n_in,
                              void* d_out, int out_size, void* d_ws, size_t ws_size,
                              hipStream_t stream) {
  const float* x = (const float*)d_in[0];
  float* out     = (float*)d_out;
  float* out_idx = out;                      // (256,7) indices as float values
  float* out_sc  = out + kBatch * 7;         // (256,7) picked scores
  float* win     = out + 2 * kBatch * 7;     // (256,96981) window scores

  appm_fused<<<kBatch * 3, kNT, 0, stream>>>(x, win, out_idx, out_sc);
}